// Round 1
// baseline (1603.308 us; speedup 1.0000x reference)
//
#include <hip/hip_runtime.h>
#include <math.h>

// Problem constants (fixed by setup_inputs): B=65536, D=256, N=1024
constexpr int DD = 256;     // feature dim
constexpr int NN = 1024;    // nodes
constexpr float C_LR = 0.3f;
constexpr float C_DSBETA = 1e-4f;
constexpr float C_EPS_DS = 1e-2f;

// ---------------- Kernel 0: per-node stats + scratch init ----------------
__global__ __launch_bounds__(256) void k_init(
    const float* __restrict__ w, const float* __restrict__ rel,
    float* __restrict__ wn2, float* __restrict__ rsum, int* __restrict__ counts,
    unsigned* __restrict__ mx_bits, unsigned* __restrict__ mn_bits,
    float* __restrict__ avgsum, int* __restrict__ n_has, float* __restrict__ loss_acc)
{
    int n = blockIdx.x, t = threadIdx.x;
    __shared__ float sA[256], sB[256];
    size_t o = (size_t)n * DD + t;
    float wv = w[o];
    sA[t] = wv * wv;
    sB[t] = rel[o];
    __syncthreads();
    #pragma unroll
    for (int s = 128; s >= 1; s >>= 1) {
        if (t < s) { sA[t] += sA[t + s]; sB[t] += sB[t + s]; }
        __syncthreads();
    }
    if (t == 0) { wn2[n] = sA[0]; rsum[n] = sB[0]; counts[n] = 0; }
    if (n == 0) {
        mx_bits[t] = 0u;              // 0.0f (ma_new >= 0 for this data)
        mn_bits[t] = 0x7F800000u;     // +inf
        avgsum[t] = 0.f;
        if (t == 0) { *n_has = 0; *loss_acc = 0.f; }
    }
}

// ---------------- Kernel 1: fused distance GEMM + act + argmax ----------------
// grid: B/64 blocks, 256 threads. Each block: 64 samples x all 1024 nodes.
constexpr int XSTR = 260;   // padded row stride (floats): 2-way-max bank conflicts

__global__ __launch_bounds__(256) void k_main(
    const float* __restrict__ x, const float* __restrict__ w,
    const float* __restrict__ ncontrol, const float* __restrict__ wn2,
    const float* __restrict__ rsum,
    int* __restrict__ idxArr, int* __restrict__ counts)
{
    __shared__ __align__(16) float x_l[64 * XSTR];
    __shared__ __align__(16) float w_l[64 * XSTR];
    __shared__ float xn2[64];

    const int t = threadIdx.x;
    const int b0 = blockIdx.x * 64;
    const float4* x4 = (const float4*)x;
    const float4* w4 = (const float4*)w;

    // load x tile [64][256] -> LDS
    #pragma unroll
    for (int p = 0; p < 16; ++p) {
        int li = p * 256 + t;
        int r = li >> 6, c = li & 63;
        float4 v = x4[(size_t)(b0 + r) * 64 + c];
        *(float4*)&x_l[r * XSTR + c * 4] = v;
    }
    __syncthreads();
    if (t < 64) {
        float s = 0.f;
        #pragma unroll 4
        for (int k = 0; k < DD; ++k) { float v = x_l[t * XSTR + k]; s += v * v; }
        xn2[t] = s;
    }
    __syncthreads();

    const int tx = t & 15, ty = t >> 4;
    unsigned long long bestk[4] = {0ull, 0ull, 0ull, 0ull};
    float acc[4][4];

    for (int nt = 0; nt < NN / 64; ++nt) {
        // load w tile [64][256] -> LDS
        #pragma unroll
        for (int p = 0; p < 16; ++p) {
            int li = p * 256 + t;
            int r = li >> 6, c = li & 63;
            float4 v = w4[(size_t)(nt * 64 + r) * 64 + c];
            *(float4*)&w_l[r * XSTR + c * 4] = v;
        }
        __syncthreads();

        #pragma unroll
        for (int i = 0; i < 4; ++i)
            #pragma unroll
            for (int j = 0; j < 4; ++j) acc[i][j] = 0.f;

        #pragma unroll 2
        for (int k4 = 0; k4 < DD / 4; ++k4) {
            float4 xa[4], wb[4];
            #pragma unroll
            for (int i = 0; i < 4; ++i) xa[i] = *(const float4*)&x_l[(ty * 4 + i) * XSTR + k4 * 4];
            #pragma unroll
            for (int j = 0; j < 4; ++j) wb[j] = *(const float4*)&w_l[(tx * 4 + j) * XSTR + k4 * 4];
            #pragma unroll
            for (int i = 0; i < 4; ++i)
                #pragma unroll
                for (int j = 0; j < 4; ++j)
                    acc[i][j] += xa[i].x * wb[j].x + xa[i].y * wb[j].y
                               + xa[i].z * wb[j].z + xa[i].w * wb[j].w;
        }

        // activation + running argmax
        #pragma unroll
        for (int j = 0; j < 4; ++j) {
            int n = nt * 64 + tx * 4 + j;
            float wv = wn2[n], rv = rsum[n], cv = ncontrol[n];
            #pragma unroll
            for (int i = 0; i < 4; ++i) {
                float d = xn2[ty * 4 + i] + wv - 2.f * acc[i][j];
                float dw = d * rv * (1.f / 256.f);
                if (!(dw == dw)) dw = 0.f;          // NaN -> 0
                float a = rv / (rv + dw + 1e-7f) * cv;
                unsigned ab = __float_as_uint(a);
                ab = (ab & 0x80000000u) ? ~ab : (ab | 0x80000000u);  // monotone map
                unsigned long long key =
                    ((unsigned long long)ab << 32) | (unsigned)(NN - 1 - n);
                if (key > bestk[i]) bestk[i] = key;
            }
        }
        __syncthreads();   // before next w-tile overwrite (and before reduction alias)
    }

    // cross-thread argmax reduction (reuse w_l)
    unsigned long long* red = (unsigned long long*)w_l;
    #pragma unroll
    for (int i = 0; i < 4; ++i) red[(ty * 4 + i) * 17 + tx] = bestk[i];
    __syncthreads();
    if (t < 64) {
        unsigned long long m = red[t * 17];
        #pragma unroll
        for (int q = 1; q < 16; ++q) { unsigned long long v = red[t * 17 + q]; if (v > m) m = v; }
        unsigned ab = (unsigned)(m >> 32);
        unsigned fb = (ab & 0x80000000u) ? (ab & 0x7FFFFFFFu) : ~ab;
        float amax = __uint_as_float(fb);
        int n = (NN - 1) - (int)(m & 0xFFFFFFFFull);
        int b = b0 + t;
        if (amax >= 0.0f) {          // AT = 0.0
            idxArr[b] = n;
            atomicAdd(&counts[n], 1);
        } else {
            idxArr[b] = -1;
        }
    }
}

// ---------------- Kernel 2: prefix sum of counts ----------------
__global__ __launch_bounds__(256) void k_scan(
    const int* __restrict__ counts, int* __restrict__ offsets, int* __restrict__ cursor)
{
    __shared__ int s[256];
    int t = threadIdx.x;
    int base = t * 4;
    int c0 = counts[base], c1 = counts[base + 1], c2 = counts[base + 2], c3 = counts[base + 3];
    int loc = c0 + c1 + c2 + c3;
    s[t] = loc;
    __syncthreads();
    for (int off = 1; off < 256; off <<= 1) {
        int v = (t >= off) ? s[t - off] : 0;
        __syncthreads();
        s[t] += v;
        __syncthreads();
    }
    int excl = s[t] - loc;
    offsets[base] = excl;           cursor[base] = excl;
    offsets[base + 1] = excl + c0;  cursor[base + 1] = excl + c0;
    offsets[base + 2] = excl + c0 + c1;      cursor[base + 2] = excl + c0 + c1;
    offsets[base + 3] = excl + c0 + c1 + c2; cursor[base + 3] = excl + c0 + c1 + c2;
}

// ---------------- Kernel 3: counting-sort scatter ----------------
__global__ __launch_bounds__(256) void k_scatter(
    const int* __restrict__ idxArr, int* __restrict__ cursor, int* __restrict__ order)
{
    int b = blockIdx.x * 256 + threadIdx.x;
    int n = idxArr[b];
    if (n >= 0) {
        int p = atomicAdd(&cursor[n], 1);
        order[p] = b;
    }
}

// ---------------- Kernel 4: per-node mean + updates + cross-node reductions ----------------
__global__ __launch_bounds__(256) void k_node(
    const float* __restrict__ x, const float* __restrict__ w, const float* __restrict__ ma,
    const int* __restrict__ counts, const int* __restrict__ offsets, const int* __restrict__ order,
    float* __restrict__ out_avg, float* __restrict__ out_w, float* __restrict__ out_ma,
    unsigned* __restrict__ mx_bits, unsigned* __restrict__ mn_bits,
    float* __restrict__ avgsum, int* __restrict__ n_has, float* __restrict__ loss_acc)
{
    int n = blockIdx.x, t = threadIdx.x;
    int cnt = counts[n], base = offsets[n];
    float s = 0.f;
    for (int j = 0; j < cnt; ++j) {
        int b = order[base + j];
        s += x[(size_t)b * DD + t];
    }
    bool has = cnt > 0;
    float avg = has ? s / (float)cnt : 0.f;   // sums / max(counts,1)
    size_t o = (size_t)n * DD + t;
    float wv = w[o], mav = ma[o];
    out_avg[o] = avg;
    float dist = fabsf(avg - wv);
    const float a = C_LR * C_DSBETA;
    float man = a * dist + (1.f - a) * mav;
    out_ma[o] = has ? man : mav;
    float delta = has ? C_LR * (avg - wv) : 0.f;
    out_w[o] = wv + delta;
    if (has) {
        atomicMax(&mx_bits[t], __float_as_uint(man));   // man >= 0
        atomicMin(&mn_bits[t], __float_as_uint(man));
        atomicAdd(&avgsum[t], man);
        if (t == 0) atomicAdd(n_has, 1);
    }
    __shared__ float rs[256];
    rs[t] = delta;
    __syncthreads();
    #pragma unroll
    for (int s2 = 128; s2 >= 1; s2 >>= 1) {
        if (t < s2) rs[t] += rs[t + s2];
        __syncthreads();
    }
    if (t == 0) atomicAdd(loss_acc, rs[0]);
}

// ---------------- Kernel 5: relevance update + loss ----------------
__global__ __launch_bounds__(256) void k_rel(
    const float* __restrict__ rel_in, const float* __restrict__ out_ma,
    const int* __restrict__ counts,
    const unsigned* __restrict__ mx_bits, const unsigned* __restrict__ mn_bits,
    const float* __restrict__ avgsum, const int* __restrict__ n_has,
    const float* __restrict__ loss_acc,
    float* __restrict__ out_rel, float* __restrict__ out_loss, float invB)
{
    int n = blockIdx.x, t = threadIdx.x;
    size_t o = (size_t)n * DD + t;
    bool has = counts[n] > 0;
    float r;
    if (has) {
        float nh = fmaxf((float)(*n_has), 1.f);
        float avg = avgsum[t] / nh;
        float mx = __uint_as_float(mx_bits[t]);
        float mn = __uint_as_float(mn_bits[t]);
        float man = out_ma[o];                 // == ma_new for has-nodes
        float targ = (man - avg) / (C_EPS_DS * (mx - mn));
        float e = expf(targ);
        float rr = 1.f / (1.f + e);
        if (!(rr == rr)) rr = 1.f;             // NaN -> 1
        r = rr;
    } else {
        r = rel_in[o];
    }
    out_rel[o] = r;
    if (n == 0 && t == 0) *out_loss = (*loss_acc) * invB;
}

// ---------------- launch ----------------
extern "C" void kernel_launch(void* const* d_in, const int* in_sizes, int n_in,
                              void* d_out, int out_size, void* d_ws, size_t ws_size,
                              hipStream_t stream)
{
    const float* x   = (const float*)d_in[0];
    const float* w   = (const float*)d_in[1];
    const float* ma  = (const float*)d_in[2];
    const float* rel = (const float*)d_in[3];
    const float* nc  = (const float*)d_in[4];

    const int B = in_sizes[0] / DD;           // 65536
    const int ND = NN * DD;                   // 262144

    float* out      = (float*)d_out;
    float* out_avg  = out;
    float* out_w    = out + ND;
    float* out_ma   = out + 2 * ND;
    float* out_rel  = out + 3 * ND;
    float* out_loss = out + 4 * ND;

    char* ws = (char*)d_ws;
    size_t off = 0;
    int* idxArr   = (int*)(ws + off); off += (size_t)B * 4;
    int* order    = (int*)(ws + off); off += (size_t)B * 4;
    int* counts   = (int*)(ws + off); off += NN * 4;
    int* offsets  = (int*)(ws + off); off += NN * 4;
    int* cursor   = (int*)(ws + off); off += NN * 4;
    float* wn2    = (float*)(ws + off); off += NN * 4;
    float* rsum   = (float*)(ws + off); off += NN * 4;
    unsigned* mxb = (unsigned*)(ws + off); off += DD * 4;
    unsigned* mnb = (unsigned*)(ws + off); off += DD * 4;
    float* avgsum = (float*)(ws + off); off += DD * 4;
    int* n_has    = (int*)(ws + off); off += 256;
    float* loss_a = (float*)(ws + off); off += 256;

    k_init<<<NN, 256, 0, stream>>>(w, rel, wn2, rsum, counts, mxb, mnb, avgsum, n_has, loss_a);
    k_main<<<B / 64, 256, 0, stream>>>(x, w, nc, wn2, rsum, idxArr, counts);
    k_scan<<<1, 256, 0, stream>>>(counts, offsets, cursor);
    k_scatter<<<B / 256, 256, 0, stream>>>(idxArr, cursor, order);
    k_node<<<NN, 256, 0, stream>>>(x, w, ma, counts, offsets, order,
                                   out_avg, out_w, out_ma, mxb, mnb, avgsum, n_has, loss_a);
    k_rel<<<NN, 256, 0, stream>>>(rel, out_ma, counts, mxb, mnb, avgsum, n_has, loss_a,
                                  out_rel, out_loss, 1.0f / (float)B);
}

// Round 4
// 749.326 us; speedup vs baseline: 2.1397x; 2.1397x over previous
//
#include <hip/hip_runtime.h>
#include <math.h>

// Problem constants (fixed by setup_inputs): B=65536, D=256, N=1024
constexpr int DD = 256;
constexpr int NN = 1024;
constexpr float C_LR = 0.3f;
constexpr float C_DSBETA = 1e-4f;
constexpr float C_EPS_DS = 1e-2f;

using short8  = __attribute__((ext_vector_type(8))) short;   // 8 bf16 (4 VGPR)
using f32x16  = __attribute__((ext_vector_type(16))) float;  // 32x32 accumulator

__device__ __forceinline__ unsigned short f2bf(float f) {
    unsigned u = __float_as_uint(f);
    u += 0x7FFF + ((u >> 16) & 1);          // round-to-nearest-even
    return (unsigned short)(u >> 16);
}
__device__ __forceinline__ float bf2f(unsigned short h) {
    return __uint_as_float(((unsigned)h) << 16);
}

// ---------------- Kernel 0: per-node stats, W bf16 hi/lo split, scratch init ----
__global__ __launch_bounds__(256) void k_init(
    const float* __restrict__ w, const float* __restrict__ rel,
    unsigned short* __restrict__ wh_g, unsigned short* __restrict__ wl_g,
    float* __restrict__ wn2, float* __restrict__ rsum,
    int* __restrict__ counts, float* __restrict__ sums,
    unsigned* __restrict__ mx_bits, unsigned* __restrict__ mn_bits,
    float* __restrict__ avgsum, int* __restrict__ n_has, float* __restrict__ loss_acc)
{
    int n = blockIdx.x, t = threadIdx.x;
    size_t o = (size_t)n * DD + t;
    float wv = w[o];
    unsigned short hi = f2bf(wv);
    float lo = wv - bf2f(hi);               // exact (Sterbenz)
    wh_g[o] = hi;
    wl_g[o] = f2bf(lo);
    sums[o] = 0.f;
    __shared__ float sA[256], sB[256];
    sA[t] = wv * wv; sB[t] = rel[o];
    __syncthreads();
    #pragma unroll
    for (int s = 128; s >= 1; s >>= 1) {
        if (t < s) { sA[t] += sA[t + s]; sB[t] += sB[t + s]; }
        __syncthreads();
    }
    if (t == 0) { wn2[n] = sA[0]; rsum[n] = sB[0]; counts[n] = 0; }
    if (n == 0) {
        mx_bits[t] = 0u;                    // ma_new >= 0 for this data
        mn_bits[t] = 0x7F800000u;           // +inf
        avgsum[t] = 0.f;
        if (t == 0) { *n_has = 0; *loss_acc = 0.f; }
    }
}

// ---------------- Kernel 1: MFMA distance GEMM + act + top2 argmax + fp64 rescore
//                  + segment-sum ----
// grid: B/64 blocks, 256 threads (4 waves, 2M x 2N). Wave owns 32 samples x 32 nodes.
__global__ __launch_bounds__(256, 2) void k_main(
    const float* __restrict__ x, const float* __restrict__ wf,
    const unsigned short* __restrict__ wh_g, const unsigned short* __restrict__ wl_g,
    const float* __restrict__ ncontrol, const float* __restrict__ wn2,
    const float* __restrict__ rsum,
    int* __restrict__ counts, float* __restrict__ sums)
{
    __shared__ __align__(16) unsigned char smem[65536];  // w_hi 32K | w_lo 32K
    __shared__ float xn2_l[64];
    __shared__ unsigned long long key_l[64][2][2];       // [row][wn][best,second]
    __shared__ int cand_l[64][2];
    __shared__ double resc[64][2];
    __shared__ int bmu_l[64];

    const int t = threadIdx.x;
    const int lane = t & 63;
    const int w = t >> 6;
    const int wm = w >> 1, wn = w & 1;
    const int m0 = wm * 32;
    const int l31 = lane & 31, half = lane >> 5;
    const int bb = blockIdx.x * 64;

    // ---- x rows -> registers, split to bf16 hi/lo; per-row norm^2 ----
    const int grow = bb + m0 + l31;
    short8 xh[16], xl[16];
    float xn2p = 0.f;
    const float* xr = x + (size_t)grow * DD + half * 8;
    #pragma unroll
    for (int s = 0; s < 16; ++s) {
        float4 a = *(const float4*)(xr + s * 16);
        float4 b = *(const float4*)(xr + s * 16 + 4);
        float f[8] = {a.x, a.y, a.z, a.w, b.x, b.y, b.z, b.w};
        #pragma unroll
        for (int j = 0; j < 8; ++j) {
            xn2p += f[j] * f[j];
            unsigned short hi = f2bf(f[j]);
            float lo = f[j] - bf2f(hi);
            xh[s][j] = (short)hi;
            xl[s][j] = (short)f2bf(lo);
        }
    }
    xn2p += __shfl_xor(xn2p, 32);           // combine k-halves of same row
    if (wn == 0 && half == 0) xn2_l[m0 + l31] = xn2p;
    __syncthreads();

    // hoist xn2 for this lane's 16 accumulator rows (C: row=(r&3)+8*(r>>2)+4*half)
    float xn2r[16];
    #pragma unroll
    for (int r = 0; r < 16; ++r)
        xn2r[r] = xn2_l[m0 + (r & 3) + 8 * (r >> 2) + 4 * half];

    unsigned long long bestk[16], bestk2[16];
    #pragma unroll
    for (int r = 0; r < 16; ++r) { bestk[r] = 0ull; bestk2[r] = 0ull; }

    const int swz = l31 << 4;               // XOR swizzle: 32 nodes -> 32 distinct 16B slots
    const int nlrow = wn * 32 + l31;        // node row within the 64-node tile
    const unsigned char* bhbase = smem + nlrow * 512;
    const unsigned char* blbase = smem + 32768 + nlrow * 512;

    for (int nt = 0; nt < 16; ++nt) {
        int ng = nt * 64 + nlrow;
        float wn2v = wn2[ng], rsv = rsum[ng], ncv = ncontrol[ng];

        // stage w tile (bf16 hi/lo), swizzled writes (uniform XOR per row -> conflict-free)
        #pragma unroll
        for (int p = 0; p < 16; ++p) {
            int g = p * 256 + t;
            int r = g >> 6, c = g & 63;
            size_t go = (size_t)(nt * 64 + r) * DD + c * 4;
            int loff = r * 512 + ((c * 8) ^ ((r & 31) << 4));
            *(ushort4*)(smem + loff)         = *(const ushort4*)(wh_g + go);
            *(ushort4*)(smem + 32768 + loff) = *(const ushort4*)(wl_g + go);
        }
        __syncthreads();

        f32x16 acc;
        #pragma unroll
        for (int r = 0; r < 16; ++r) acc[r] = 0.f;

        #pragma unroll
        for (int s = 0; s < 16; ++s) {
            int koff = (s * 32 + half * 16) ^ swz;
            short8 bh = *(const short8*)(bhbase + koff);
            short8 bl = *(const short8*)(blbase + koff);
            acc = __builtin_amdgcn_mfma_f32_32x32x16_bf16(xh[s], bh, acc, 0, 0, 0);
            acc = __builtin_amdgcn_mfma_f32_32x32x16_bf16(xl[s], bh, acc, 0, 0, 0);
            acc = __builtin_amdgcn_mfma_f32_32x32x16_bf16(xh[s], bl, acc, 0, 0, 0);
        }

        // activation + running top-2 (act > 0 always: rsum>0, den>0, nc>=0)
        float rvd  = rsv * (1.f / 256.f);
        float den0 = rsv + 1e-7f;
        float num  = rsv * ncv;
        unsigned inv_n = (unsigned)(NN - 1 - ng);
        #pragma unroll
        for (int r = 0; r < 16; ++r) {
            float d   = xn2r[r] + wn2v - 2.f * acc[r];
            float den = den0 + d * rvd;
            float act = num * __builtin_amdgcn_rcpf(den);
            unsigned long long key =
                ((unsigned long long)(__float_as_uint(act) | 0x80000000u) << 32) | inv_n;
            if (key > bestk[r]) { bestk2[r] = bestk[r]; bestk[r] = key; }
            else if (key > bestk2[r]) bestk2[r] = key;
        }
        __syncthreads();                    // guard next tile's staging
    }

    // top-2 merge across the 32 lanes sharing the same rows (same half)
    #pragma unroll
    for (int mask = 1; mask <= 16; mask <<= 1) {
        #pragma unroll
        for (int r = 0; r < 16; ++r) {
            unsigned long long ob = __shfl_xor(bestk[r], mask);
            unsigned long long os = __shfl_xor(bestk2[r], mask);
            if (ob > bestk[r]) {
                bestk2[r] = (bestk[r] > os) ? bestk[r] : os;
                bestk[r]  = ob;
            } else {
                if (ob > bestk2[r]) bestk2[r] = ob;
            }
        }
    }
    if (l31 == 0) {
        #pragma unroll
        for (int r = 0; r < 16; ++r) {
            int mrow = (r & 3) + 8 * (r >> 2) + 4 * half;
            key_l[m0 + mrow][wn][0] = bestk[r];
            key_l[m0 + mrow][wn][1] = bestk2[r];
        }
    }
    __syncthreads();

    // merge the two node-halves -> global top-2 candidates per sample
    if (t < 64) {
        unsigned long long b0k = key_l[t][0][0], s0k = key_l[t][0][1];
        unsigned long long b1k = key_l[t][1][0], s1k = key_l[t][1][1];
        unsigned long long B, S;
        if (b0k > b1k) { B = b0k; S = (s0k > b1k) ? s0k : b1k; }
        else           { B = b1k; S = (s1k > b0k) ? s1k : b0k; }
        cand_l[t][0] = (NN - 1) - (int)(B & 0xFFFFFFFFull);
        cand_l[t][1] = (NN - 1) - (int)(S & 0xFFFFFFFFull);
    }
    __syncthreads();

    // fp64 exact rescore of the two candidates (t<128: 64 samples x 2 cands)
    if (t < 128) {
        int s = t >> 1, c = t & 1;
        int node = cand_l[s][c];
        const float* xr2 = x + (size_t)(bb + s) * DD;
        const float* wr2 = wf + (size_t)node * DD;
        double a = 0.0;
        #pragma unroll 4
        for (int k = 0; k < DD; k += 4) {
            float4 xv = *(const float4*)(xr2 + k);
            float4 wv = *(const float4*)(wr2 + k);
            double d0 = (double)xv.x - (double)wv.x;
            double d1 = (double)xv.y - (double)wv.y;
            double d2 = (double)xv.z - (double)wv.z;
            double d3 = (double)xv.w - (double)wv.w;
            a += d0 * d0 + d1 * d1 + d2 * d2 + d3 * d3;
        }
        double rs = (double)rsum[node];
        double dw = a * rs * (1.0 / 256.0);
        double act = rs / (rs + dw + 1e-7) * (double)ncontrol[node];
        resc[s][c] = act;
    }
    __syncthreads();

    if (t < 64) {
        int c0 = cand_l[t][0], c1 = cand_l[t][1];
        double a0 = resc[t][0], a1 = resc[t][1];
        int bmu = c0;
        if (a1 > a0 || (a1 == a0 && c1 < c0)) bmu = c1;
        bmu_l[t] = bmu;
        atomicAdd(&counts[bmu], 1);
    }
    __syncthreads();

    // coalesced atomic segment-sum into global sums[bmu][t] (exact x from global, L2-hot)
    #pragma unroll 4
    for (int s2 = 0; s2 < 64; ++s2) {
        atomicAdd(&sums[(size_t)bmu_l[s2] * DD + t], x[(size_t)(bb + s2) * DD + t]);
    }
}

// ---------------- Kernel 2: per-node updates + cross-node reductions ----------
__global__ __launch_bounds__(256) void k_node(
    const float* __restrict__ w, const float* __restrict__ ma,
    const int* __restrict__ counts, const float* __restrict__ sums,
    float* __restrict__ out_avg, float* __restrict__ out_w, float* __restrict__ out_ma,
    unsigned* __restrict__ mx_bits, unsigned* __restrict__ mn_bits,
    float* __restrict__ avgsum, int* __restrict__ n_has, float* __restrict__ loss_acc)
{
    int n = blockIdx.x, t = threadIdx.x;
    int cnt = counts[n];
    size_t o = (size_t)n * DD + t;
    bool has = cnt > 0;
    float avg = has ? sums[o] / (float)cnt : 0.f;
    float wv = w[o], mav = ma[o];
    out_avg[o] = avg;
    float dist = fabsf(avg - wv);
    const float a = C_LR * C_DSBETA;
    float man = a * dist + (1.f - a) * mav;
    out_ma[o] = has ? man : mav;
    float delta = has ? C_LR * (avg - wv) : 0.f;
    out_w[o] = wv + delta;
    if (has) {
        atomicMax(&mx_bits[t], __float_as_uint(man));
        atomicMin(&mn_bits[t], __float_as_uint(man));
        atomicAdd(&avgsum[t], man);
        if (t == 0) atomicAdd(n_has, 1);
    }
    __shared__ float rs[256];
    rs[t] = delta;
    __syncthreads();
    #pragma unroll
    for (int s2 = 128; s2 >= 1; s2 >>= 1) {
        if (t < s2) rs[t] += rs[t + s2];
        __syncthreads();
    }
    if (t == 0) atomicAdd(loss_acc, rs[0]);
}

// ---------------- Kernel 3: relevance update + loss ----------------
__global__ __launch_bounds__(256) void k_rel(
    const float* __restrict__ rel_in, const float* __restrict__ out_ma,
    const int* __restrict__ counts,
    const unsigned* __restrict__ mx_bits, const unsigned* __restrict__ mn_bits,
    const float* __restrict__ avgsum, const int* __restrict__ n_has,
    const float* __restrict__ loss_acc,
    float* __restrict__ out_rel, float* __restrict__ out_loss, float invB)
{
    int n = blockIdx.x, t = threadIdx.x;
    size_t o = (size_t)n * DD + t;
    bool has = counts[n] > 0;
    float r;
    if (has) {
        float nh  = fmaxf((float)(*n_has), 1.f);
        float avg = avgsum[t] / nh;
        float mx  = __uint_as_float(mx_bits[t]);
        float mn  = __uint_as_float(mn_bits[t]);
        float man = out_ma[o];
        float targ = (man - avg) / (C_EPS_DS * (mx - mn));
        float e = expf(targ);
        float rr = 1.f / (1.f + e);
        if (!(rr == rr)) rr = 1.f;          // NaN -> 1
        r = rr;
    } else {
        r = rel_in[o];
    }
    out_rel[o] = r;
    if (n == 0 && t == 0) *out_loss = (*loss_acc) * invB;
}

// ---------------- launch ----------------
extern "C" void kernel_launch(void* const* d_in, const int* in_sizes, int n_in,
                              void* d_out, int out_size, void* d_ws, size_t ws_size,
                              hipStream_t stream)
{
    const float* x   = (const float*)d_in[0];
    const float* w   = (const float*)d_in[1];
    const float* ma  = (const float*)d_in[2];
    const float* rel = (const float*)d_in[3];
    const float* nc  = (const float*)d_in[4];

    const int B = in_sizes[0] / DD;           // 65536
    const int ND = NN * DD;                   // 262144

    float* out      = (float*)d_out;
    float* out_avg  = out;
    float* out_w    = out + ND;
    float* out_ma   = out + 2 * ND;
    float* out_rel  = out + 3 * ND;
    float* out_loss = out + 4 * ND;

    char* ws = (char*)d_ws;
    size_t off = 0;
    float* sums   = (float*)(ws + off); off += (size_t)ND * 4;       // 1 MB
    unsigned short* wh_g = (unsigned short*)(ws + off); off += (size_t)ND * 2;
    unsigned short* wl_g = (unsigned short*)(ws + off); off += (size_t)ND * 2;
    int* counts   = (int*)(ws + off); off += NN * 4;
    float* wn2    = (float*)(ws + off); off += NN * 4;
    float* rsum   = (float*)(ws + off); off += NN * 4;
    unsigned* mxb = (unsigned*)(ws + off); off += DD * 4;
    unsigned* mnb = (unsigned*)(ws + off); off += DD * 4;
    float* avgsum = (float*)(ws + off); off += DD * 4;
    int* n_has    = (int*)(ws + off); off += 256;
    float* loss_a = (float*)(ws + off); off += 256;

    k_init<<<NN, 256, 0, stream>>>(w, rel, wh_g, wl_g, wn2, rsum, counts, sums,
                                   mxb, mnb, avgsum, n_has, loss_a);
    k_main<<<B / 64, 256, 0, stream>>>(x, w, wh_g, wl_g, nc, wn2, rsum, counts, sums);
    k_node<<<NN, 256, 0, stream>>>(w, ma, counts, sums,
                                   out_avg, out_w, out_ma, mxb, mnb, avgsum, n_has, loss_a);
    k_rel<<<NN, 256, 0, stream>>>(rel, out_ma, counts, mxb, mnb, avgsum, n_has, loss_a,
                                  out_rel, out_loss, 1.0f / (float)B);
}